// Round 1
// baseline (99.013 us; speedup 1.0000x reference)
//
#include <hip/hip_runtime.h>
#include <math.h>

#define CH 16   // channels staged per block

__global__ __launch_bounds__(256) void roialign_kernel(
    const float* __restrict__ feat, const float* __restrict__ bbox,
    float* __restrict__ out) {
  __shared__ float lds[CH * 1024];           // 16 planes of 32x32 f32 = 64 KB
  __shared__ int   sx0[14], sx1[14], sy0v[14], sy1v[14];
  __shared__ float swx[14], swy[14];

  const int blk = blockIdx.x;
  const int n  = blk >> 4;                   // 16 channel-chunks per box
  const int c0 = (blk & 15) * CH;
  const int t  = threadIdx.x;

  const float bx1 = bbox[n * 4 + 0];
  const float by1 = bbox[n * 4 + 1];
  const float bx2 = bbox[n * 4 + 2];
  const float by2 = bbox[n * 4 + 3];
  const float xstep = (bx2 - bx1) * (1.0f / 14.0f);
  const float ystep = (by2 - by1) * (1.0f / 14.0f);

  // ---- per-block coordinate tables (threads 0..27) ----
  if (t < 14) {
    float xs = bx1 + (float)t * xstep;
    float x0 = fminf(fmaxf(floorf(xs), 0.0f), 31.0f);
    int x0i = (int)x0;
    sx0[t] = x0i;
    sx1[t] = min(x0i + 1, 31);
    swx[t] = xs - x0;
  } else if (t < 28) {
    int g = t - 14;
    float yv = by1 + (float)g * ystep;
    float y0 = fminf(fmaxf(floorf(yv), 0.0f), 31.0f);
    int y0i = (int)y0;
    sy0v[g] = y0i;
    sy1v[g] = min(y0i + 1, 31);
    swy[g] = yv - y0;
  }

  // ---- row range actually touched by the 14 y samples ----
  // y0i min = clamp(floor(ys[0])), y1i max = min(clamp(floor(ys[13]))+1, 31)
  int ylo = min(max((int)floorf(by1), 0), 31);
  float ys13 = by1 + 13.0f * ystep;
  int yhi = min(min(max((int)floorf(ys13), 0), 31) + 1, 31);
  const int R = yhi - ylo + 1;               // rows to stage (<= 32)
  const int perch = R * 8;                   // float4 per channel
  const int total = CH * perch;

  // ---- coalesced global -> LDS staging (only rows [ylo..yhi]) ----
  const float4* __restrict__ src =
      (const float4*)(feat + (size_t)n * (256 * 1024));
  float4* dst = (float4*)lds;
  const int base4 = ylo * 8;
  for (int i = t; i < total; i += 256) {
    int c   = i / perch;
    int rem = i - c * perch;
    int off = base4 + rem;
    dst[c * 256 + off] = src[(size_t)(c0 + c) * 256 + off];
  }
  __syncthreads();

  // ---- compute: CH*49 = 784 outputs, coalesced contiguous write ----
  float* outp = out + ((size_t)n * 256 + c0) * 49;
  for (int o = t; o < CH * 49; o += 256) {
    int cl = o / 49;                         // const divisor -> magic mul
    int s  = o - cl * 49;
    int sy = s / 7;
    int sx = s - sy * 7;
    const float* plane = lds + cl * 1024;
    float m = -INFINITY;
#pragma unroll
    for (int i = 0; i < 2; ++i) {
      int   y0o = sy0v[2 * sy + i] * 32;
      int   y1o = sy1v[2 * sy + i] * 32;
      float wy  = swy[2 * sy + i];
#pragma unroll
      for (int j = 0; j < 2; ++j) {
        int   gx  = 2 * sx + j;
        int   x0i = sx0[gx];
        int   x1i = sx1[gx];
        float wx  = swx[gx];
        float v00 = plane[y0o + x0i];
        float v01 = plane[y0o + x1i];
        float v10 = plane[y1o + x0i];
        float v11 = plane[y1o + x1i];
        float top = fmaf(wx, v01 - v00, v00);
        float bot = fmaf(wx, v11 - v10, v10);
        float val = fmaf(wy, bot - top, top);
        m = fmaxf(m, val);
      }
    }
    outp[o] = m;
  }
}

extern "C" void kernel_launch(void* const* d_in, const int* in_sizes, int n_in,
                              void* d_out, int out_size, void* d_ws, size_t ws_size,
                              hipStream_t stream) {
  const float* feat = (const float*)d_in[0];
  const float* bbox = (const float*)d_in[1];
  float* out = (float*)d_out;
  dim3 grid(512 * (256 / CH));               // 8192 blocks
  roialign_kernel<<<grid, 256, 0, stream>>>(feat, bbox, out);
}

// Round 2
// 64.242 us; speedup vs baseline: 1.5413x; 1.5413x over previous
//
#include <hip/hip_runtime.h>
#include <math.h>

#define CH 8   // channels staged per block (32 KB LDS -> 5 blocks/CU)

__global__ __launch_bounds__(256, 5) void roialign_kernel(
    const float* __restrict__ feat, const float* __restrict__ bbox,
    float* __restrict__ out) {
  __shared__ float lds[CH * 1024];           // 8 planes of 32x32 f32 = 32 KB
  __shared__ int   sx0[14], sx1[14], sy0v[14], sy1v[14];
  __shared__ float swx[14], swy[14];

  const int blk = blockIdx.x;
  const int n  = blk >> 5;                   // 32 channel-chunks per box
  const int c0 = (blk & 31) * CH;
  const int t  = threadIdx.x;

  const float bx1 = bbox[n * 4 + 0];
  const float by1 = bbox[n * 4 + 1];
  const float bx2 = bbox[n * 4 + 2];
  const float by2 = bbox[n * 4 + 3];
  const float xstep = (bx2 - bx1) * (1.0f / 14.0f);
  const float ystep = (by2 - by1) * (1.0f / 14.0f);

  // ---- per-block coordinate tables (threads 0..27) ----
  if (t < 14) {
    float xs = bx1 + (float)t * xstep;
    float x0 = fminf(fmaxf(floorf(xs), 0.0f), 31.0f);
    int x0i = (int)x0;
    sx0[t] = x0i;
    sx1[t] = min(x0i + 1, 31);
    swx[t] = xs - x0;
  } else if (t < 28) {
    int g = t - 14;
    float yv = by1 + (float)g * ystep;
    float y0 = fminf(fmaxf(floorf(yv), 0.0f), 31.0f);
    int y0i = (int)y0;
    sy0v[g] = y0i;
    sy1v[g] = min(y0i + 1, 31);
    swy[g] = yv - y0;
  }

  // ---- row range actually touched by the 14 y samples ----
  const int ylo = min(max((int)floorf(by1), 0), 31);
  const float ys13 = by1 + 13.0f * ystep;
  const int yhi = min(min(max((int)floorf(ys13), 0), 31) + 1, 31);
  const int perch = (yhi - ylo + 1) * 8;     // float4 per channel

  // ---- coalesced global -> LDS staging: 32 threads per channel ----
  // no runtime division: c = t>>5, lane = t&31, stride-32 over row span
  {
    const float4* __restrict__ src =
        (const float4*)(feat + (size_t)n * (256 * 1024));
    float4* dst = (float4*)lds;
    const int c    = t >> 5;
    const int lane = t & 31;
    const int cb   = c * 256 + ylo * 8;
    const size_t gb = (size_t)(c0 + c) * 256 + ylo * 8;
    for (int off = lane; off < perch; off += 32) {
      dst[cb + off] = src[gb + off];
    }
  }
  __syncthreads();

  // ---- compute: CH*49 = 392 outputs, coalesced contiguous write ----
  float* outp = out + ((size_t)n * 256 + c0) * 49;
  for (int o = t; o < CH * 49; o += 256) {
    int cl = o / 49;                         // const divisor -> magic mul
    int s  = o - cl * 49;
    int sy = s / 7;
    int sx = s - sy * 7;
    const float* plane = lds + cl * 1024;
    float m = -INFINITY;
#pragma unroll
    for (int i = 0; i < 2; ++i) {
      int   y0o = sy0v[2 * sy + i] * 32;
      int   y1o = sy1v[2 * sy + i] * 32;
      float wy  = swy[2 * sy + i];
#pragma unroll
      for (int j = 0; j < 2; ++j) {
        int   gx  = 2 * sx + j;
        int   x0i = sx0[gx];
        int   x1i = sx1[gx];
        float wx  = swx[gx];
        float v00 = plane[y0o + x0i];
        float v01 = plane[y0o + x1i];
        float v10 = plane[y1o + x0i];
        float v11 = plane[y1o + x1i];
        float top = fmaf(wx, v01 - v00, v00);
        float bot = fmaf(wx, v11 - v10, v10);
        float val = fmaf(wy, bot - top, top);
        m = fmaxf(m, val);
      }
    }
    outp[o] = m;
  }
}

extern "C" void kernel_launch(void* const* d_in, const int* in_sizes, int n_in,
                              void* d_out, int out_size, void* d_ws, size_t ws_size,
                              hipStream_t stream) {
  const float* feat = (const float*)d_in[0];
  const float* bbox = (const float*)d_in[1];
  float* out = (float*)d_out;
  dim3 grid(512 * (256 / CH));               // 16384 blocks
  roialign_kernel<<<grid, 256, 0, stream>>>(feat, bbox, out);
}

// Round 3
// 51.323 us; speedup vs baseline: 1.9292x; 1.2517x over previous
//
#include <hip/hip_runtime.h>
#include <math.h>

#define CH 8      // channels staged per block
#define RMAX 22   // max sampled row span (bbox generator guarantees <= 21)
// LDS: 8 planes x 22 rows x 32 cols x 4 B = 22.5 KB -> 7 blocks/CU (28 waves)

__global__ __launch_bounds__(256, 7) void roialign_kernel(
    const float* __restrict__ feat, const float* __restrict__ bbox,
    float* __restrict__ out) {
  __shared__ float lds[CH * RMAX * 32];
  __shared__ int   sx0[14], sx1[14], sy0o[14], sy1o[14];  // y tables pre-scaled by 32
  __shared__ float swx[14], swy[14];

  const int blk = blockIdx.x;
  const int n  = blk >> 5;                   // 32 channel-chunks per box
  const int c0 = (blk & 31) * CH;
  const int t  = threadIdx.x;

  const float bx1 = bbox[n * 4 + 0];
  const float by1 = bbox[n * 4 + 1];
  const float bx2 = bbox[n * 4 + 2];
  const float by2 = bbox[n * 4 + 3];
  const float xstep = (bx2 - bx1) * (1.0f / 14.0f);
  const float ystep = (by2 - by1) * (1.0f / 14.0f);

  // ---- row range touched by the 14 y samples ----
  const int ylo = min(max((int)floorf(by1), 0), 31);
  const float ys13 = by1 + 13.0f * ystep;
  int yhi = min(min(max((int)floorf(ys13), 0), 31) + 1, 31);
  yhi = min(yhi, ylo + (RMAX - 1));          // defensive: never overflow LDS
  const int perch = (yhi - ylo + 1) * 8;     // float4 per packed plane

  // ---- per-block coordinate tables (threads 0..27) ----
  if (t < 14) {
    float xs = bx1 + (float)t * xstep;
    float x0 = fminf(fmaxf(floorf(xs), 0.0f), 31.0f);
    int x0i = (int)x0;
    sx0[t] = x0i;
    sx1[t] = min(x0i + 1, 31);
    swx[t] = xs - x0;
  } else if (t < 28) {
    int g = t - 14;
    float yv = by1 + (float)g * ystep;
    float y0 = fminf(fmaxf(floorf(yv), 0.0f), 31.0f);
    int y0i = (int)y0;
    int y1i = min(y0i + 1, 31);
    y0i = min(max(y0i, ylo), yhi);           // stays within staged span
    y1i = min(max(y1i, ylo), yhi);
    sy0o[g] = (y0i - ylo) * 32;              // pre-scaled row offset
    sy1o[g] = (y1i - ylo) * 32;
    swy[g] = yv - y0;
  }

  // ---- coalesced global -> LDS staging: 32 threads per channel, packed rows ----
  {
    const float4* __restrict__ src =
        (const float4*)(feat + (size_t)n * (256 * 1024));
    float4* dst = (float4*)lds;
    const int c    = t >> 5;
    const int lane = t & 31;
    const int cb   = c * (RMAX * 8);         // packed plane base (float4 units)
    const size_t gb = (size_t)(c0 + c) * 256 + ylo * 8;
    for (int off = lane; off < perch; off += 32) {
      dst[cb + off] = src[gb + off];
    }
  }
  __syncthreads();

  // ---- compute: CH*49 = 392 outputs, coalesced contiguous write ----
  float* outp = out + ((size_t)n * 256 + c0) * 49;
  for (int o = t; o < CH * 49; o += 256) {
    int cl = o / 49;                         // const divisor -> magic mul
    int s  = o - cl * 49;
    int sy = s / 7;
    int sx = s - sy * 7;
    const float* plane = lds + cl * (RMAX * 32);
    float m = -INFINITY;
#pragma unroll
    for (int i = 0; i < 2; ++i) {
      int   y0o = sy0o[2 * sy + i];
      int   y1o = sy1o[2 * sy + i];
      float wy  = swy[2 * sy + i];
#pragma unroll
      for (int j = 0; j < 2; ++j) {
        int   gx  = 2 * sx + j;
        int   x0i = sx0[gx];
        int   x1i = sx1[gx];
        float wx  = swx[gx];
        float v00 = plane[y0o + x0i];
        float v01 = plane[y0o + x1i];
        float v10 = plane[y1o + x0i];
        float v11 = plane[y1o + x1i];
        float top = fmaf(wx, v01 - v00, v00);
        float bot = fmaf(wx, v11 - v10, v10);
        float val = fmaf(wy, bot - top, top);
        m = fmaxf(m, val);
      }
    }
    outp[o] = m;
  }
}

extern "C" void kernel_launch(void* const* d_in, const int* in_sizes, int n_in,
                              void* d_out, int out_size, void* d_ws, size_t ws_size,
                              hipStream_t stream) {
  const float* feat = (const float*)d_in[0];
  const float* bbox = (const float*)d_in[1];
  float* out = (float*)d_out;
  dim3 grid(512 * (256 / CH));               // 16384 blocks
  roialign_kernel<<<grid, 256, 0, stream>>>(feat, bbox, out);
}

// Round 4
// 45.838 us; speedup vs baseline: 2.1601x; 1.1196x over previous
//
#include <hip/hip_runtime.h>
#include <math.h>

#define CH 8      // channels staged per block
#define RMAX 22   // max sampled row span (bbox generator guarantees <= 21)
// LDS: 8 planes x 22 rows x 32 cols x 4 B = 22.5 KB -> 7 blocks/CU (28 waves)
// Swizzle: row yr of channel cl stores float4-group q at (q + yr + cl) & 7.
// Bank of element x = (((x>>2)+yr+cl)&7)*4 + (x&3): same x on different
// rows/channels -> different bank groups (kills the 7-way x-conflicts).

__global__ __launch_bounds__(256, 7) void roialign_kernel(
    const float* __restrict__ feat, const float* __restrict__ bbox,
    float* __restrict__ out) {
  __shared__ float lds[CH * RMAX * 32];
  __shared__ int   sxg0[14], sxl0[14], sxg1[14], sxl1[14];  // x>>2, x&3
  __shared__ int   sy0r[14], sy1r[14];                      // row idx (y - ylo)
  __shared__ float swx[14], swy[14];

  const int blk = blockIdx.x;
  const int n  = blk >> 5;                   // 32 channel-chunks per box
  const int c0 = (blk & 31) * CH;
  const int t  = threadIdx.x;

  const float bx1 = bbox[n * 4 + 0];
  const float by1 = bbox[n * 4 + 1];
  const float bx2 = bbox[n * 4 + 2];
  const float by2 = bbox[n * 4 + 3];
  const float xstep = (bx2 - bx1) * (1.0f / 14.0f);
  const float ystep = (by2 - by1) * (1.0f / 14.0f);

  // ---- row range touched by the 14 y samples ----
  const int ylo = min(max((int)floorf(by1), 0), 31);
  const float ys13 = by1 + 13.0f * ystep;
  int yhi = min(min(max((int)floorf(ys13), 0), 31) + 1, 31);
  yhi = min(yhi, ylo + (RMAX - 1));          // defensive: never overflow LDS
  const int perch = (yhi - ylo + 1) * 8;     // float4 per packed plane

  // ---- per-block coordinate tables (threads 0..27) ----
  if (t < 14) {
    float xs = bx1 + (float)t * xstep;
    float x0 = fminf(fmaxf(floorf(xs), 0.0f), 31.0f);
    int x0i = (int)x0;
    int x1i = min(x0i + 1, 31);
    sxg0[t] = x0i >> 2;
    sxl0[t] = x0i & 3;
    sxg1[t] = x1i >> 2;
    sxl1[t] = x1i & 3;
    swx[t] = xs - x0;
  } else if (t < 28) {
    int g = t - 14;
    float yv = by1 + (float)g * ystep;
    float y0 = fminf(fmaxf(floorf(yv), 0.0f), 31.0f);
    int y0i = (int)y0;
    int y1i = min(y0i + 1, 31);
    y0i = min(max(y0i, ylo), yhi);           // stays within staged span
    y1i = min(max(y1i, ylo), yhi);
    sy0r[g] = y0i - ylo;                     // row index within staged span
    sy1r[g] = y1i - ylo;
    swy[g] = yv - y0;
  }

  // ---- coalesced global -> LDS staging, swizzled f4 groups ----
  {
    const float4* __restrict__ src =
        (const float4*)(feat + (size_t)n * (256 * 1024));
    float4* dst = (float4*)lds;
    const int c    = t >> 5;
    const int lane = t & 31;
    const int cb   = c * (RMAX * 8);         // packed plane base (float4 units)
    const size_t gb = (size_t)(c0 + c) * 256 + ylo * 8;
    for (int off = lane; off < perch; off += 32) {
      int yr = off >> 3;
      int q  = off & 7;
      int sq = (q + yr + c) & 7;
      dst[cb + yr * 8 + sq] = src[gb + off];
    }
  }
  __syncthreads();

  // ---- compute: CH*49 = 392 outputs, coalesced contiguous write ----
  float* outp = out + ((size_t)n * 256 + c0) * 49;
  for (int o = t; o < CH * 49; o += 256) {
    int cl = o / 49;                         // const divisor -> magic mul
    int s  = o - cl * 49;
    int sy = s / 7;
    int sx = s - sy * 7;
    const float* plane = lds + cl * (RMAX * 32);
    float m = -INFINITY;
#pragma unroll
    for (int i = 0; i < 2; ++i) {
      int   yr0 = sy0r[2 * sy + i];
      int   yr1 = sy1r[2 * sy + i];
      float wy  = swy[2 * sy + i];
      const float* r0 = plane + yr0 * 32;
      const float* r1 = plane + yr1 * 32;
      const int rot0 = yr0 + cl;
      const int rot1 = yr1 + cl;
#pragma unroll
      for (int j = 0; j < 2; ++j) {
        int   gx  = 2 * sx + j;
        int   xg0 = sxg0[gx], xl0 = sxl0[gx];
        int   xg1 = sxg1[gx], xl1 = sxl1[gx];
        float wx  = swx[gx];
        float v00 = r0[(((xg0 + rot0) & 7) << 2) + xl0];
        float v01 = r0[(((xg1 + rot0) & 7) << 2) + xl1];
        float v10 = r1[(((xg0 + rot1) & 7) << 2) + xl0];
        float v11 = r1[(((xg1 + rot1) & 7) << 2) + xl1];
        float top = fmaf(wx, v01 - v00, v00);
        float bot = fmaf(wx, v11 - v10, v10);
        float val = fmaf(wy, bot - top, top);
        m = fmaxf(m, val);
      }
    }
    outp[o] = m;
  }
}

extern "C" void kernel_launch(void* const* d_in, const int* in_sizes, int n_in,
                              void* d_out, int out_size, void* d_ws, size_t ws_size,
                              hipStream_t stream) {
  const float* feat = (const float*)d_in[0];
  const float* bbox = (const float*)d_in[1];
  float* out = (float*)d_out;
  dim3 grid(512 * (256 / CH));               // 16384 blocks
  roialign_kernel<<<grid, 256, 0, stream>>>(feat, bbox, out);
}

// Round 5
// 45.399 us; speedup vs baseline: 2.1810x; 1.0097x over previous
//
#include <hip/hip_runtime.h>
#include <math.h>

#define CH   4    // channels per block, one per wave (4 waves x 64)
#define RPAD 24   // padded row capacity: 3 chunks of 8 rows (span <= 22)
// LDS: 4 planes x 24 rows x 32 f32 = 12 KB -> 8 blocks/CU (32 waves, full).
// Staging: global_load_lds width=16, LINEAR dest; the bank swizzle is applied
// on the GLOBAL source address instead (lane (yr,q) fetches global group
// (q - yr - c) & 7), so reads rotate with (xg + yr + cl) & 7 as before.

typedef __attribute__((address_space(1))) const void gptr_t;
typedef __attribute__((address_space(3))) void lptr_t;

__global__ __launch_bounds__(256, 8) void roialign_kernel(
    const float* __restrict__ feat, const float* __restrict__ bbox,
    float* __restrict__ out) {
  __shared__ float lds[CH * RPAD * 32];
  __shared__ int   sxg0[14], sxl0[14], sxg1[14], sxl1[14];  // x>>2, x&3
  __shared__ int   sy0r[14], sy1r[14];                      // dest row idx
  __shared__ float swx[14], swy[14];

  const int blk = blockIdx.x;
  const int n  = blk >> 6;                   // 64 channel-chunks per box
  const int c0 = (blk & 63) * CH;
  const int t  = threadIdx.x;
  const int wv = t >> 6;                     // wave id == channel within chunk
  const int ln = t & 63;

  const float bx1 = bbox[n * 4 + 0];
  const float by1 = bbox[n * 4 + 1];
  const float bx2 = bbox[n * 4 + 2];
  const float by2 = bbox[n * 4 + 3];
  const float xstep = (bx2 - bx1) * (1.0f / 14.0f);
  const float ystep = (by2 - by1) * (1.0f / 14.0f);

  // ---- row range touched by the 14 y samples ----
  const int ylo = min(max((int)floorf(by1), 0), 31);
  const float ys13 = by1 + 13.0f * ystep;
  int yhi = min(min(max((int)floorf(ys13), 0), 31) + 1, 31);
  yhi = min(yhi, ylo + (RPAD - 1));          // defensive: never overflow LDS
  const int R = yhi - ylo + 1;               // rows needed (<= 22)

  // ---- per-block coordinate tables (threads 0..27) ----
  if (t < 14) {
    float xs = bx1 + (float)t * xstep;
    float x0 = fminf(fmaxf(floorf(xs), 0.0f), 31.0f);
    int x0i = (int)x0;
    int x1i = min(x0i + 1, 31);
    sxg0[t] = x0i >> 2;
    sxl0[t] = x0i & 3;
    sxg1[t] = x1i >> 2;
    sxl1[t] = x1i & 3;
    swx[t] = xs - x0;
  } else if (t < 28) {
    int g = t - 14;
    float yv = by1 + (float)g * ystep;
    float y0 = fminf(fmaxf(floorf(yv), 0.0f), 31.0f);
    int y0i = (int)y0;
    int y1i = min(y0i + 1, 31);
    y0i = min(max(y0i, ylo), yhi);           // stays within staged span
    y1i = min(max(y1i, ylo), yhi);
    sy0r[g] = y0i - ylo;                     // dest row index
    sy1r[g] = y1i - ylo;
    swy[g] = yv - y0;
  }

  // ---- DMA staging: wave wv stages channel wv, 8 rows / 1 KB per call ----
  {
    const float* srcbase =
        feat + (size_t)n * (256 * 1024) + (size_t)(c0 + wv) * 1024;
    float* dstbase = lds + wv * (RPAD * 32);
    const int yr_l = ln >> 3;                // row within 8-row chunk
    const int q    = ln & 7;                 // dest float4 group
    for (int it = 0; it * 8 < R; ++it) {     // block-uniform trip count
      int yr   = it * 8 + yr_l;              // dest row
      int srow = min(yr, R - 1);             // clamp tail rows (L1 hit)
      int qp   = (q - yr - wv) & 7;          // pre-swizzled source group
      const float* gp = srcbase + (ylo + srow) * 32 + qp * 4;
      lptr_t* lp = (lptr_t*)(dstbase + it * 256);   // wave-uniform dest
      __builtin_amdgcn_global_load_lds((gptr_t*)gp, lp, 16, 0, 0);
    }
  }
  asm volatile("s_waitcnt vmcnt(0)" ::: "memory");
  __syncthreads();

  // ---- compute: wave wv -> channel wv, lane s<49 -> one 7x7 output ----
  if (ln < 49) {
    const int sy = ln / 7;                   // const divisor -> magic mul
    const int sx = ln - sy * 7;
    const float* plane = lds + wv * (RPAD * 32);
    float m = -INFINITY;
#pragma unroll
    for (int i = 0; i < 2; ++i) {
      int   yr0 = sy0r[2 * sy + i];
      int   yr1 = sy1r[2 * sy + i];
      float wy  = swy[2 * sy + i];
      const float* r0 = plane + yr0 * 32;
      const float* r1 = plane + yr1 * 32;
      const int rot0 = yr0 + wv;
      const int rot1 = yr1 + wv;
#pragma unroll
      for (int j = 0; j < 2; ++j) {
        int   gx  = 2 * sx + j;
        int   xg0 = sxg0[gx], xl0 = sxl0[gx];
        int   xg1 = sxg1[gx], xl1 = sxl1[gx];
        float wx  = swx[gx];
        float v00 = r0[(((xg0 + rot0) & 7) << 2) + xl0];
        float v01 = r0[(((xg1 + rot0) & 7) << 2) + xl1];
        float v10 = r1[(((xg0 + rot1) & 7) << 2) + xl0];
        float v11 = r1[(((xg1 + rot1) & 7) << 2) + xl1];
        float top = fmaf(wx, v01 - v00, v00);
        float bot = fmaf(wx, v11 - v10, v10);
        float val = fmaf(wy, bot - top, top);
        m = fmaxf(m, val);
      }
    }
    out[((size_t)n * 256 + c0 + wv) * 49 + ln] = m;
  }
}

extern "C" void kernel_launch(void* const* d_in, const int* in_sizes, int n_in,
                              void* d_out, int out_size, void* d_ws, size_t ws_size,
                              hipStream_t stream) {
  const float* feat = (const float*)d_in[0];
  const float* bbox = (const float*)d_in[1];
  float* out = (float*)d_out;
  dim3 grid(512 * (256 / CH));               // 32768 blocks
  roialign_kernel<<<grid, 256, 0, stream>>>(feat, bbox, out);
}